// Round 5
// baseline (80.567 us; speedup 1.0000x reference)
//
#include <hip/hip_runtime.h>

// TemporalJitter: out[b,pos,:] = x[b, src(b,pos), :] where
// src(b,pos) = max{ t : t + shifts[b,t] == pos, 0<=t<T }, else zeros.
// |shift| <= 2, so candidates are t in [pos-2, pos+2] — scan high->low.
//
// B=64, T=128, N=8192 (fp32).
// Cache-partition strategy: x (256 MB) == L3 capacity exactly, and the same
// cyclic access order every graph replay makes LRU thrash (~0% hits, round-4
// arithmetic). Fix: statically partition x rows — 75% (192 MB, fits L3 with
// headroom) read CACHED so they stay resident across replays; 25% read NT
// (never allocate) and stream from HBM. Writes are NT (don't evict x).
// Steady state HBM/replay: 256 MB write + ~50 MB read.

#define B_DIM 64
#define T_DIM 128
#define N_DIM 8192
#define N4    (N_DIM / 4)   // 2048 float4 per row
#define MAX_SHIFT 2

typedef float f4 __attribute__((ext_vector_type(4)));

__global__ __launch_bounds__(256) void temporal_jitter_kernel(
    const f4* __restrict__ x,
    const int* __restrict__ shifts,
    f4* __restrict__ out)
{
    const int row = blockIdx.x;          // row = b*T + pos
    const int b   = row >> 7;            // / T_DIM
    const int pos = row & (T_DIM - 1);

    // Find the source timestep: largest t in [pos-2, pos+2] with t+shift==pos.
    int src = -1;
    const int lo = pos - MAX_SHIFT < 0 ? 0 : pos - MAX_SHIFT;
    const int hi = pos + MAX_SHIFT > T_DIM - 1 ? T_DIM - 1 : pos + MAX_SHIFT;
    #pragma unroll
    for (int t = hi; t >= lo; --t) {
        if (shifts[b * T_DIM + t] == pos - t) { src = t; break; }
    }

    f4* __restrict__ dst = out + (size_t)row * N4;

    if (src >= 0) {
        const int srow_idx = b * T_DIM + src;        // global x row index
        const f4* __restrict__ srow = x + (size_t)srow_idx * N4;
        if ((srow_idx & 3) == 0) {
            // Streaming subset (25%): nt load, never allocates in L3.
            #pragma unroll
            for (int i = threadIdx.x; i < N4; i += 256) {
                f4 v = __builtin_nontemporal_load(&srow[i]);
                __builtin_nontemporal_store(v, &dst[i]);
            }
        } else {
            // Pinned subset (75% = 192 MB): cached load, L3-resident across replays.
            #pragma unroll
            for (int i = threadIdx.x; i < N4; i += 256) {
                f4 v = srow[i];
                __builtin_nontemporal_store(v, &dst[i]);
            }
        }
    } else {
        const f4 z = {0.f, 0.f, 0.f, 0.f};
        #pragma unroll
        for (int i = threadIdx.x; i < N4; i += 256) {
            __builtin_nontemporal_store(z, &dst[i]);
        }
    }
}

extern "C" void kernel_launch(void* const* d_in, const int* in_sizes, int n_in,
                              void* d_out, int out_size, void* d_ws, size_t ws_size,
                              hipStream_t stream)
{
    const f4*  x      = (const f4*)d_in[0];
    const int* shifts = (const int*)d_in[1];
    f4*        out    = (f4*)d_out;

    dim3 grid(B_DIM * T_DIM);   // 8192 blocks, one per output row
    dim3 block(256);
    temporal_jitter_kernel<<<grid, block, 0, stream>>>(x, shifts, out);
}

// Round 6
// 70.039 us; speedup vs baseline: 1.1503x; 1.1503x over previous
//
#include <hip/hip_runtime.h>

// TemporalJitter: out[b,pos,:] = x[b, src(b,pos), :] where
// src(b,pos) = max{ t : t + shifts[b,t] == pos, 0<=t<T }, else zeros.
// |shift| <= 2, so candidates are t in [pos-2, pos+2] — scan high->low.
//
// B=64, T=128, N=8192 (fp32). Best-known config (round 4, 70.1 us):
//   - cached (normal) loads: nt loads demote to a slow read path on gfx950
//     (A/B/C: all-nt 87.6 us, 25%-nt 80.6 us, 0%-nt 70.1 us)
//   - nt stores: avoid write-allocate/eviction churn on the 256 MB output
//     stream (+25% vs cached stores)
//   - L3 cross-replay residency is structurally dead: 454 MB/replay cyclic
//     through a 256 MB memory-side cache -> thrash regardless of hints.
// Traffic: 256 MB write + ~198 MB read = 454 MB -> 6.48 TB/s effective,
// above the 6.29 TB/s measured copy ceiling. This is the roofline.

#define B_DIM 64
#define T_DIM 128
#define N_DIM 8192
#define N4    (N_DIM / 4)   // 2048 float4 per row
#define MAX_SHIFT 2

typedef float f4 __attribute__((ext_vector_type(4)));

__global__ __launch_bounds__(256) void temporal_jitter_kernel(
    const f4* __restrict__ x,
    const int* __restrict__ shifts,
    f4* __restrict__ out)
{
    const int row = blockIdx.x;          // row = b*T + pos
    const int b   = row >> 7;            // / T_DIM
    const int pos = row & (T_DIM - 1);

    // Find the source timestep: largest t in [pos-2, pos+2] with t+shift==pos.
    int src = -1;
    const int lo = pos - MAX_SHIFT < 0 ? 0 : pos - MAX_SHIFT;
    const int hi = pos + MAX_SHIFT > T_DIM - 1 ? T_DIM - 1 : pos + MAX_SHIFT;
    #pragma unroll
    for (int t = hi; t >= lo; --t) {
        if (shifts[b * T_DIM + t] == pos - t) { src = t; break; }
    }

    f4* __restrict__ dst = out + (size_t)row * N4;

    if (src >= 0) {
        const f4* __restrict__ srow = x + ((size_t)b * T_DIM + src) * N4;
        #pragma unroll
        for (int i = threadIdx.x; i < N4; i += 256) {
            f4 v = srow[i];                          // cached load
            __builtin_nontemporal_store(v, &dst[i]); // nt store
        }
    } else {
        const f4 z = {0.f, 0.f, 0.f, 0.f};
        #pragma unroll
        for (int i = threadIdx.x; i < N4; i += 256) {
            __builtin_nontemporal_store(z, &dst[i]);
        }
    }
}

extern "C" void kernel_launch(void* const* d_in, const int* in_sizes, int n_in,
                              void* d_out, int out_size, void* d_ws, size_t ws_size,
                              hipStream_t stream)
{
    const f4*  x      = (const f4*)d_in[0];
    const int* shifts = (const int*)d_in[1];
    f4*        out    = (f4*)d_out;

    dim3 grid(B_DIM * T_DIM);   // 8192 blocks, one per output row
    dim3 block(256);
    temporal_jitter_kernel<<<grid, block, 0, stream>>>(x, shifts, out);
}